// Round 8
// baseline (196.343 us; speedup 1.0000x reference)
//
#include <hip/hip_runtime.h>

// Problem constants
#define B_  2
#define S_  2048
#define D_  1024
#define H_  16
#define HD_ 64
#define N3_ 3072      // 3*D
#define M_  4096      // B*S

typedef _Float16 f16;
typedef _Float16 f16x2 __attribute__((ext_vector_type(2)));
typedef _Float16 f16x4 __attribute__((ext_vector_type(4)));
typedef _Float16 f16x8 __attribute__((ext_vector_type(8)));
typedef float    f32x4 __attribute__((ext_vector_type(4)));

// ---------------------------------------------------------------------------
// async global->LDS, 16B per lane. LDS dest must be wave-uniform base+lane*16.
__device__ __forceinline__ void async16(const f16* g, f16* l) {
  __builtin_amdgcn_global_load_lds(
      (const __attribute__((address_space(1))) unsigned int*)g,
      (__attribute__((address_space(3))) unsigned int*)l, 16, 0, 0);
}

__device__ __forceinline__ f16x2 pkrtz(float a, float b) {
  return __builtin_bit_cast(f16x2, __builtin_amdgcn_cvt_pkrtz(a, b));
}

// ---------------------------------------------------------------------------
// f32 -> f16 convert with scale (vectorized, n4 = n/4)
__global__ __launch_bounds__(256)
void cvt_f32_f16(const float* __restrict__ src, f16* __restrict__ dst,
                 int n4, float scale) {
  int i = blockIdx.x * 256 + threadIdx.x;
  if (i >= n4) return;
  float4 v = ((const float4*)src)[i];
  f16x4 o = { (f16)(v.x * scale), (f16)(v.y * scale),
              (f16)(v.z * scale), (f16)(v.w * scale) };
  ((f16x4*)dst)[i] = o;
}

// all 4 weight matrices in one launch; dst = wqkv|wo16 contiguous (4*D*D)
__global__ __launch_bounds__(256)
void cvt_weights(const float* __restrict__ Wq, const float* __restrict__ Wk,
                 const float* __restrict__ Wv, const float* __restrict__ Wo,
                 f16* __restrict__ dst, float qscale) {
  const int m = blockIdx.y;
  const float* src = (m == 0) ? Wq : (m == 1) ? Wk : (m == 2) ? Wv : Wo;
  const float scale = (m == 0) ? qscale : 1.0f;
  int i = blockIdx.x * 256 + threadIdx.x;           // over D*D/4
  float4 v = ((const float4*)src)[i];
  f16x4 o = { (f16)(v.x * scale), (f16)(v.y * scale),
              (f16)(v.z * scale), (f16)(v.w * scale) };
  ((f16x4*)(dst + (size_t)m * D_ * D_))[i] = o;
}

// ---------------------------------------------------------------------------
// Double-buffered NT GEMM: C[m,n] = sum_k A[m,k]*Bw[n,k]. 128x128 tile,
// 4 waves, BK=64. Pipeline: stage tile kt+1 via async16 into buf[(kt+1)&1]
// right AFTER the barrier, then compute tile kt from buf[kt&1] — loads have
// a full compute phase in flight before the next barrier's vmcnt drain.
// One barrier per iteration. LDS 64 KB -> 2 blocks/CU.
// Staging: 16 segs of 1KB (8 rows x 128B); wave w stages segs w,4+w,8+w,12+w;
// phys chunk p at row r holds global k-chunk p^(r&7) (XOR swizzle).
// QKV=1: f16 out to Cq for Q/K col-blocks (mask on K); V col-blocks
//        (n0>=2048) write V^T into vtout (fused transpose + mask).
// QKV=0: f32 out to Cf with bias.
template<int QKV>
__global__ __launch_bounds__(256)
void gemm_nt(const f16* __restrict__ A, const f16* __restrict__ Bw,
             f16* __restrict__ Cq, float* __restrict__ Cf,
             f16* __restrict__ vtout,
             const float* __restrict__ mask, const float* __restrict__ bias,
             int Ndim, int Kdim) {
  __shared__ f16 As[2][128 * 64];
  __shared__ f16 Bs[2][128 * 64];

  const int tid  = threadIdx.x;
  const int lane = tid & 63;
  const int w    = tid >> 6;
  const int lcol = lane & 15;
  const int quad = lane >> 4;
  const int lx   = lcol & 7;
  const int wave_m = w >> 1, wave_n = w & 1;

  const int m0 = blockIdx.y * 128;
  const int n0 = blockIdx.x * 128;

  const int rr  = lane >> 3;          // row within 8-row segment
  const int gch = (lane & 7) ^ rr;    // global k-chunk this lane fetches

  const f16* gA[4];
  const f16* gB[4];
  int soff[4];                        // seg LDS offset (f16 elems), wave-uniform
#pragma unroll
  for (int i = 0; i < 4; i++) {
    int seg = i * 4 + w;
    int row = seg * 8 + rr;
    gA[i] = A  + (size_t)(m0 + row) * Kdim + gch * 8;
    gB[i] = Bw + (size_t)(n0 + row) * Kdim + gch * 8;
    soff[i] = seg * 512;
  }

  auto stage = [&](int k0, int buf) {
#pragma unroll
    for (int i = 0; i < 4; i++) async16(gA[i] + k0, As[buf] + soff[i]);
#pragma unroll
    for (int i = 0; i < 4; i++) async16(gB[i] + k0, Bs[buf] + soff[i]);
  };

  int offA[4], offB[4];
#pragma unroll
  for (int i = 0; i < 4; i++) {
    offA[i] = (wave_m * 64 + i * 16 + lcol) * 64;
    offB[i] = (wave_n * 64 + i * 16 + lcol) * 64;
  }

  const f32x4 zero = {0.f, 0.f, 0.f, 0.f};
  f32x4 acc[4][4];
#pragma unroll
  for (int i = 0; i < 4; i++)
#pragma unroll
    for (int j = 0; j < 4; j++) acc[i][j] = zero;

  const int niter = Kdim >> 6;
  stage(0, 0);
  for (int it = 0; it < niter; it++) {
    __syncthreads();                    // drains vmcnt -> tile it landed
    if (it + 1 < niter) stage((it + 1) << 6, (it + 1) & 1);  // in flight

    const f16* Ab = As[it & 1];
    const f16* Bb = Bs[it & 1];
#pragma unroll
    for (int ks = 0; ks < 2; ks++) {
      const int co = ((quad + 4 * ks) ^ lx) * 8;
      f16x8 af[4], bf[4];
#pragma unroll
      for (int i = 0; i < 4; i++) af[i] = *(const f16x8*)(Ab + offA[i] + co);
#pragma unroll
      for (int i = 0; i < 4; i++) bf[i] = *(const f16x8*)(Bb + offB[i] + co);
#pragma unroll
      for (int mi = 0; mi < 4; mi++)
#pragma unroll
        for (int ni = 0; ni < 4; ni++)
          acc[mi][ni] = __builtin_amdgcn_mfma_f32_16x16x32_f16(
              af[mi], bf[ni], acc[mi][ni], 0, 0, 0);
    }
  }

  if (QKV && n0 >= 2 * D_) {
    // V column-block: fused transpose. vt[(b*16+h)*64+hd][s] with pad mask.
#pragma unroll
    for (int mi = 0; mi < 4; mi++) {
      const int mgb = m0 + wave_m * 64 + mi * 16 + quad * 4;
      const int b = mgb >> 11, s = mgb & (S_ - 1);
      const float mk0 = mask[mgb], mk1 = mask[mgb + 1];
      const float mk2 = mask[mgb + 2], mk3 = mask[mgb + 3];
#pragma unroll
      for (int ni = 0; ni < 4; ni++) {
        const int vcol = n0 - 2 * D_ + wave_n * 64 + ni * 16 + lcol;
        f16x4 v = { (f16)(acc[mi][ni][0] * mk0), (f16)(acc[mi][ni][1] * mk1),
                    (f16)(acc[mi][ni][2] * mk2), (f16)(acc[mi][ni][3] * mk3) };
        *(f16x4*)(vtout +
                  ((size_t)(b * 16 + (vcol >> 6)) * 64 + (vcol & 63)) * S_ + s) = v;
      }
    }
  } else {
    const bool kmask = QKV && (n0 >= D_);
#pragma unroll
    for (int mi = 0; mi < 4; mi++) {
#pragma unroll
      for (int r = 0; r < 4; r++) {
        int mg = m0 + wave_m * 64 + mi * 16 + quad * 4 + r;
        float mk = kmask ? mask[mg] : 1.0f;
#pragma unroll
        for (int ni = 0; ni < 4; ni++) {
          int ng = n0 + wave_n * 64 + ni * 16 + lcol;
          float v = acc[mi][ni][r] * mk;
          if (QKV) Cq[(size_t)mg * Ndim + ng] = (f16)v;
          else     Cf[(size_t)mg * Ndim + ng] = v + bias[ng];
        }
      }
    }
  }
}

// ---------------------------------------------------------------------------
// Flash attention v5: dual-supertile + no-max softmax (round 6) with
// DOUBLE-BUFFERED K/V staging: stage kt+1 right after the barrier, compute
// kt from the other buffer; one barrier per iteration.
__global__ __launch_bounds__(256)
void flash_attn5(const f16* __restrict__ qkv, const f16* __restrict__ vt,
                 f16* __restrict__ ctx) {
  __shared__ f16 Ks[2][64 * 64];   // [key][hd], 128B rows, chunk-swizzled
  __shared__ f16 Vs[2][64 * 64];   // [hd][key]

  const int tid  = threadIdx.x;
  const int lane = tid & 63;
  const int w    = tid >> 6;
  const int lcol = lane & 15;
  const int quad = lane >> 4;
  const int lx   = lcol & 7;

  const int id   = blockIdx.x;
  const int bh   = (id & 7) + 8 * ((id >> 3) & 3);
  const int pair = id >> 5;                  // 0..15
  const int b    = bh >> 4, h = bh & 15;
  const int qtA  = 31 - pair;                // big supertile
  const int qtB  = pair;                     // small supertile

  const int rsub = lane >> 3;
  const int gch  = (lane & 7) ^ rsub;
  const int ko0  = (w * 8) * 64;             // wave-uniform LDS seg offsets
  const int ko1  = (32 + w * 8) * 64;
  const int krow0 = w * 8 + rsub;
  const int krow1 = 32 + w * 8 + rsub;
  const f16* Kg = qkv + (size_t)b * S_ * N3_ + D_ + h * HD_;  // row stride N3
  const f16* Vg = vt + (size_t)bh * HD_ * S_;                 // row stride S

  auto stage = [&](int kt, int buf) {
    const int kbase = kt * 64;
    async16(Kg + (size_t)(kbase + krow0) * N3_ + gch * 8, Ks[buf] + ko0);
    async16(Kg + (size_t)(kbase + krow1) * N3_ + gch * 8, Ks[buf] + ko1);
    async16(Vg + (size_t)krow0 * S_ + kbase + gch * 8, Vs[buf] + ko0);
    async16(Vg + (size_t)krow1 * S_ + kbase + gch * 8, Vs[buf] + ko1);
  };

  const f32x4 zero = {0.f, 0.f, 0.f, 0.f};

  const int qrowA = qtA * 64 + w * 16 + lcol;
  const int qrowB = qtB * 64 + w * 16 + lcol;
  const f16* QpA = qkv + (size_t)(b * S_ + qrowA) * N3_ + h * HD_;
  const f16* QpB = qkv + (size_t)(b * S_ + qrowB) * N3_ + h * HD_;
  const f16x8 qbA0 = *(const f16x8*)(QpA + quad * 8);
  const f16x8 qbA1 = *(const f16x8*)(QpA + 32 + quad * 8);
  const f16x8 qbB0 = *(const f16x8*)(QpB + quad * 8);
  const f16x8 qbB1 = *(const f16x8*)(QpB + 32 + quad * 8);

  f32x4 oA[4], oB[4];
  float lpA = 0.f, lpB = 0.f;
#pragma unroll
  for (int i = 0; i < 4; i++) { oA[i] = zero; oB[i] = zero; }

  auto mask_diag = [&](f32x4* sc) {
#pragma unroll
    for (int ct = 0; ct < 4; ct++) {
      int koff = ct * 16 + quad * 4;
      int qoff = w * 16 + lcol;
#pragma unroll
      for (int r = 0; r < 4; r++)
        if (koff + r > qoff) sc[ct][r] = -1e30f;
    }
  };
  auto softmax_tiles = [&](f32x4* sc, f16x4* pf, float& lp) {
#pragma unroll
    for (int ct = 0; ct < 4; ct++) {
      float e0 = exp2f(sc[ct][0]);
      float e1 = exp2f(sc[ct][1]);
      float e2 = exp2f(sc[ct][2]);
      float e3 = exp2f(sc[ct][3]);
      lp += (e0 + e1) + (e2 + e3);
      f16x2 lo = pkrtz(e0, e1);
      f16x2 hi = pkrtz(e2, e3);
      f16x4 p = { lo[0], lo[1], hi[0], hi[1] };
      pf[ct] = p;
    }
  };

  stage(0, 0);
  for (int kt = 0; kt <= qtA; kt++) {
    __syncthreads();                 // drains vmcnt -> tile kt landed
    if (kt + 1 <= qtA) stage(kt + 1, (kt + 1) & 1);

    const f16* Kb = Ks[kt & 1];
    const f16* Vb = Vs[kt & 1];
    const bool doB = (kt <= qtB);

    f16x8 kf0[4], kf1[4];
    f32x4 scA[4], scB[4];
#pragma unroll
    for (int ct = 0; ct < 4; ct++) {
      const f16* kr = Kb + (ct * 16 + lcol) * 64;
      kf0[ct] = *(const f16x8*)(kr + ((quad    ) ^ lx) * 8);
      kf1[ct] = *(const f16x8*)(kr + ((quad + 4) ^ lx) * 8);
      f32x4 z = zero;
      z = __builtin_amdgcn_mfma_f32_16x16x32_f16(kf0[ct], qbA0, z, 0, 0, 0);
      z = __builtin_amdgcn_mfma_f32_16x16x32_f16(kf1[ct], qbA1, z, 0, 0, 0);
      scA[ct] = z;
    }
    if (doB) {
#pragma unroll
      for (int ct = 0; ct < 4; ct++) {
        f32x4 z = zero;
        z = __builtin_amdgcn_mfma_f32_16x16x32_f16(kf0[ct], qbB0, z, 0, 0, 0);
        z = __builtin_amdgcn_mfma_f32_16x16x32_f16(kf1[ct], qbB1, z, 0, 0, 0);
        scB[ct] = z;
      }
    }

    if (kt == qtA) mask_diag(scA);
    if (doB && kt == qtB) mask_diag(scB);

    f16x4 pfA[4], pfB[4];
    softmax_tiles(scA, pfA, lpA);
    if (doB) softmax_tiles(scB, pfB, lpB);

#pragma unroll
    for (int ht = 0; ht < 4; ht++) {
      const f16* vr = Vb + (ht * 16 + lcol) * 64 + (quad & 1) * 4;
      f16x4 vf[4];
#pragma unroll
      for (int ct = 0; ct < 4; ct++)
        vf[ct] = *(const f16x4*)(vr + (((2 * ct + (quad >> 1)) ^ lx) * 8));
#pragma unroll
      for (int ct = 0; ct < 4; ct++)
        oA[ht] = __builtin_amdgcn_mfma_f32_16x16x16f16(vf[ct], pfA[ct], oA[ht], 0, 0, 0);
      if (doB) {
#pragma unroll
        for (int ct = 0; ct < 4; ct++)
          oB[ht] = __builtin_amdgcn_mfma_f32_16x16x16f16(vf[ct], pfB[ct], oB[ht], 0, 0, 0);
      }
    }
  }

  lpA += __shfl_xor(lpA, 16);
  lpA += __shfl_xor(lpA, 32);
  lpB += __shfl_xor(lpB, 16);
  lpB += __shfl_xor(lpB, 32);
  const float invA = 1.f / lpA;
  const float invB = 1.f / lpB;
  f16* cpA = ctx + (size_t)(b * S_ + qrowA) * D_ + h * HD_ + quad * 4;
  f16* cpB = ctx + (size_t)(b * S_ + qrowB) * D_ + h * HD_ + quad * 4;
#pragma unroll
  for (int ht = 0; ht < 4; ht++) {
    f16x4 ovA = { (f16)(oA[ht][0] * invA), (f16)(oA[ht][1] * invA),
                  (f16)(oA[ht][2] * invA), (f16)(oA[ht][3] * invA) };
    *(f16x4*)(cpA + ht * 16) = ovA;
    f16x4 ovB = { (f16)(oB[ht][0] * invB), (f16)(oB[ht][1] * invB),
                  (f16)(oB[ht][2] * invB), (f16)(oB[ht][3] * invB) };
    *(f16x4*)(cpB + ht * 16) = ovB;
  }
}

// ---------------------------------------------------------------------------
extern "C" void kernel_launch(void* const* d_in, const int* in_sizes, int n_in,
                              void* d_out, int out_size, void* d_ws, size_t ws_size,
                              hipStream_t stream) {
  (void)in_sizes; (void)n_in; (void)out_size; (void)ws_size;
  const float* x  = (const float*)d_in[0];
  const float* am = (const float*)d_in[1];
  const float* Wq = (const float*)d_in[2];
  const float* Wk = (const float*)d_in[3];
  const float* Wv = (const float*)d_in[4];
  const float* Wo = (const float*)d_in[5];
  const float* bo = (const float*)d_in[6];
  float* out = (float*)d_out;

  f16* ws   = (f16*)d_ws;
  f16* wqkv = ws;                                   // 3*D*D   (Wq|Wk|Wv, NxK)
  f16* wo16 = wqkv + (size_t)3 * D_ * D_;           // D*D (contiguous after wqkv)
  f16* xb   = wo16 + (size_t)D_ * D_;               // M*D
  f16* qkvb = xb + (size_t)M_ * D_;                 // M*3D  (Q|K cols used)
  f16* vtb  = qkvb + (size_t)M_ * N3_;              // B*H*HD*S
  f16* ctxb = vtb + (size_t)M_ * D_;                // M*D

  const float qscale = 0.125f * 1.4426950408889634f;  // 1/sqrt(hd) * log2(e)

  cvt_f32_f16<<<dim3(M_ * D_ / 1024), 256, 0, stream>>>(x, xb, M_ * D_ / 4, 1.0f);
  cvt_weights<<<dim3(D_ * D_ / 1024, 4), 256, 0, stream>>>(Wq, Wk, Wv, Wo, wqkv, qscale);

  gemm_nt<1><<<dim3(N3_ / 128, M_ / 128), 256, 0, stream>>>(
      xb, wqkv, qkvb, nullptr, vtb, am, nullptr, N3_, D_);
  flash_attn5<<<dim3(512), 256, 0, stream>>>(qkvb, vtb, ctxb);
  gemm_nt<0><<<dim3(D_ / 128, M_ / 128), 256, 0, stream>>>(
      ctxb, wo16, nullptr, out, nullptr, nullptr, bo, D_, D_);
}